// Round 5
// baseline (104.994 us; speedup 1.0000x reference)
//
#include <hip/hip_runtime.h>

// out[b,s,i] = w * x[b,s,i] + (1-w) * x[b,s,(i+1) % C],  C = 4096.
// One circular row (4096 floats = 16 float4 groups x 64 lanes) per wave:
// all wrap neighbors are in-wave (shfl / readlane), no fallback loads,
// no divergence. Every load/store is a lane-contiguous 1KB segment.
// A/B vs R4: nontemporal hints REMOVED (only change).

typedef float f32x4 __attribute__((ext_vector_type(4)));

__global__ __launch_bounds__(256) void NormalizedCirculantMask2_kernel(
    const float* __restrict__ x,
    const float* __restrict__ wptr,
    float* __restrict__ out,
    int nrows)
{
    const float w  = wptr[0];
    const float wc = 1.0f - w;
    const int lane  = threadIdx.x & 63;
    const int wib   = threadIdx.x >> 6;                    // wave in block
    const int wpb   = blockDim.x >> 6;                     // waves per block
    int wave_id     = blockIdx.x * wpb + wib;
    int nwaves      = gridDim.x * wpb;

    for (int row = wave_id; row < nrows; row += nwaves) {
        const f32x4* xr  = reinterpret_cast<const f32x4*>(x) + (size_t)row * 1024;
        f32x4*       orp = reinterpret_cast<f32x4*>(out)    + (size_t)row * 1024;

        f32x4 v[16];
        #pragma unroll
        for (int j = 0; j < 16; ++j)
            v[j] = xr[j * 64 + lane];

        #pragma unroll
        for (int j = 0; j < 16; ++j) {
            // neighbor of this group's last element = next group's first element
            float e = __shfl(v[j].x, lane + 1);            // lane 63: garbage
            // lane 63's neighbor = (j+1)-th group's lane 0 (j=15 wraps to j=0,
            // which is exactly the circular wrap to element 0 of the row)
            int f_bits = __builtin_amdgcn_readlane(
                             __builtin_bit_cast(int, v[(j + 1) & 15].x), 0);
            float first = __builtin_bit_cast(float, f_bits);
            e = (lane == 63) ? first : e;                  // cndmask, no branch

            f32x4 o;
            o.x = w * v[j].x + wc * v[j].y;
            o.y = w * v[j].y + wc * v[j].z;
            o.z = w * v[j].z + wc * v[j].w;
            o.w = w * v[j].w + wc * e;
            orp[j * 64 + lane] = o;
        }
    }
}

extern "C" void kernel_launch(void* const* d_in, const int* in_sizes, int n_in,
                              void* d_out, int out_size, void* d_ws, size_t ws_size,
                              hipStream_t stream)
{
    const float* x    = (const float*)d_in[0];
    const float* wptr = (const float*)d_in[1];
    float* out        = (float*)d_out;

    int nrows = out_size / 4096;          // 16384 rows of C=4096
    int block = 256;                      // 4 waves/block
    int grid  = 2048;                     // 8192 waves, 2 rows each

    NormalizedCirculantMask2_kernel<<<grid, block, 0, stream>>>(x, wptr, out, nrows);
}

// Round 6
// 91.132 us; speedup vs baseline: 1.1521x; 1.1521x over previous
//
#include <hip/hip_runtime.h>

// out[b,s,i] = w * x[b,s,i] + (1-w) * x[b,s,(i+1) % C],  C = 4096.
// Half-row (2048 floats = 8 float4 groups x 64 lanes) per wave: v[8] keeps
// VGPR <= 64 -> 32 waves/CU (vs R4's 16) for deeper HBM request queues.
// Wrap neighbors in-wave via shfl/readlane; only lane 63 of the LAST group
// does one masked 4B load per half-row (the cross-wave boundary element).
// nt hints kept (R5 A/B: removing them cost +10%).

typedef float f32x4 __attribute__((ext_vector_type(4)));

__global__ __launch_bounds__(256) void NormalizedCirculantMask2_kernel(
    const float* __restrict__ x,
    const float* __restrict__ wptr,
    float* __restrict__ out,
    int nhalves)
{
    const float w  = wptr[0];
    const float wc = 1.0f - w;
    const int lane = threadIdx.x & 63;
    const int wib  = threadIdx.x >> 6;
    const int wpb  = blockDim.x >> 6;
    int wave_id    = blockIdx.x * wpb + wib;
    int nwaves     = gridDim.x * wpb;

    for (int half = wave_id; half < nhalves; half += nwaves) {
        const f32x4* xr = reinterpret_cast<const f32x4*>(x) + (size_t)half * 512;
        f32x4*       op = reinterpret_cast<f32x4*>(out)     + (size_t)half * 512;

        f32x4 v[8];
        #pragma unroll
        for (int j = 0; j < 8; ++j)
            v[j] = __builtin_nontemporal_load(xr + j * 64 + lane);

        // Boundary element: neighbor of this half-row's last element.
        // half even -> element 2048 of the row (first elem of the odd half);
        // half odd  -> element 0 of the row (circular wrap).
        float ewrap = 0.0f;
        if (lane == 63) {
            size_t base = (size_t)(half >> 1) * 4096;
            ewrap = x[(half & 1) ? base : base + 2048];
        }

        #pragma unroll
        for (int j = 0; j < 8; ++j) {
            float e = __shfl(v[j].x, lane + 1);            // lane 63: garbage
            float first;
            if (j < 7) {
                int fb = __builtin_amdgcn_readlane(
                             __builtin_bit_cast(int, v[j + 1].x), 0);
                first = __builtin_bit_cast(float, fb);
            } else {
                first = ewrap;                             // only lane 63 reads it
            }
            e = (lane == 63) ? first : e;                  // cndmask, no branch

            f32x4 o;
            o.x = w * v[j].x + wc * v[j].y;
            o.y = w * v[j].y + wc * v[j].z;
            o.z = w * v[j].z + wc * v[j].w;
            o.w = w * v[j].w + wc * e;
            __builtin_nontemporal_store(o, op + j * 64 + lane);
        }
    }
}

extern "C" void kernel_launch(void* const* d_in, const int* in_sizes, int n_in,
                              void* d_out, int out_size, void* d_ws, size_t ws_size,
                              hipStream_t stream)
{
    const float* x    = (const float*)d_in[0];
    const float* wptr = (const float*)d_in[1];
    float* out        = (float*)d_out;

    int nhalves = out_size / 2048;        // 32768 half-rows
    int block   = 256;                    // 4 waves/block
    int grid    = 2048;                   // 8192 waves, 4 half-rows each

    NormalizedCirculantMask2_kernel<<<grid, block, 0, stream>>>(x, wptr, out, nhalves);
}